// Round 1
// baseline (1150.628 us; speedup 1.0000x reference)
//
#include <hip/hip_runtime.h>
#include <math.h>

// Problem constants (fixed shapes from the reference)
#define B_IN   32
#define B_OUTC 16
#define BATCH  16
#define F_IN   16
#define F_OUT  64
#define NGRID  32            // N_ALPHA * N_BETA
#define NSPEC  256           // B_OUT^2
#define NSPEC3 5456          // sum (2l+1)^2, l<16
// scaling = 1/sqrt(NGRID * F_IN * B_OUT^4 / B_IN^2) = 1/sqrt(32768)
#define SCALING 0.005524271728019903f
#define PI_F 3.14159265358979323846f

__constant__ int c_off[17] = {0,1,10,35,84,165,286,455,680,969,1330,1771,2300,2925,3654,4495,5456};

// ---------------- Kernel 1: fhat[s][b][f] = sum_j wig_s2[j,s] * (alpha-DFT of x at m(s)) ----------------
// grid: 256 blocks = (b,f) pairs; 256 threads
__global__ __launch_bounds__(256) void k1_fhat(const float* __restrict__ x,
                                               const float* __restrict__ wig_s2,
                                               float2* __restrict__ fhat) {
    __shared__ float  xs[64 * 64];       // x[b,f,:,:]
    __shared__ float2 xf[31 * 64];       // [m+15][j]
    __shared__ float2 t64[64];           // e^{-2pi i q/64}
    const int b = blockIdx.x >> 4, f = blockIdx.x & 15;
    const int tid = threadIdx.x;

    const float4* xsrc = (const float4*)(x + (size_t)(b * F_IN + f) * 4096);
    float4* xdst = (float4*)xs;
    for (int i = tid; i < 1024; i += 256) xdst[i] = xsrc[i];
    if (tid < 64) {
        float s_, c_;
        sincosf(2.0f * PI_F * (float)tid / 64.0f, &s_, &c_);
        t64[tid] = make_float2(c_, -s_);
    }
    __syncthreads();

    // alpha DFT for m = -15..15
    for (int t = tid; t < 31 * 64; t += 256) {
        const int mi = t >> 6;           // 0..30
        const int j  = t & 63;
        const int m  = mi - 15;
        float re = 0.f, im = 0.f;
        const float* row = &xs[j * 64];
        for (int a = 0; a < 64; ++a) {
            const float v = row[a];
            const float2 w = t64[(m * a) & 63];
            re += v * w.x;
            im += v * w.y;
        }
        xf[mi * 64 + j] = make_float2(re, im);
    }
    __syncthreads();

    // beta contraction: one s per thread
    const int s = tid;
    int l = 0;
    while ((l + 1) * (l + 1) <= s) ++l;
    const int m = s - l * l - l;
    float re = 0.f, im = 0.f;
    const float2* row = &xf[(m + 15) * 64];
    for (int j = 0; j < 64; ++j) {
        const float w = wig_s2[j * NSPEC + s];
        re += row[j].x * w;
        im += row[j].y * w;
    }
    fhat[(s * BATCH + b) * F_IN + f] = make_float2(re, im);
}

// ---------------- Kernel 2: psic[s][o][i] = conj(scaling * sum_g kernel[i,o,g] * Fk[s,g]) ----------------
// grid: 256 blocks = s; 256 threads
__global__ __launch_bounds__(256) void k2_psic(const float* __restrict__ kern,
                                               const float* __restrict__ fk_re,
                                               const float* __restrict__ fk_im,
                                               float2* __restrict__ psic) {
    __shared__ float2 fk[NGRID];
    const int s = blockIdx.x;
    const int tid = threadIdx.x;
    if (tid < NGRID) fk[tid] = make_float2(fk_re[s * NGRID + tid], -fk_im[s * NGRID + tid]); // conj
    __syncthreads();
    for (int t = tid; t < F_OUT * F_IN; t += 256) {
        const int o = t >> 4, i = t & 15;
        const float* kr = kern + (size_t)(i * F_OUT + o) * NGRID;
        float re = 0.f, im = 0.f;
        for (int g = 0; g < NGRID; ++g) {
            const float v = kr[g];
            re += v * fk[g].x;
            im += v * fk[g].y;
        }
        psic[(s * F_OUT + o) * F_IN + i] = make_float2(re * SCALING, im * SCALING);
    }
}

// ---------------- Kernel 3: per (b,o): Fz -> per-k S -> column DFT -> real row DFT -> out ----------------
// grid: 1024 blocks = (b,o); 256 threads; ~59.5 KB LDS
__global__ __launch_bounds__(256) void k3_main(const float2* __restrict__ fhat,
                                               const float2* __restrict__ psic,
                                               const float* __restrict__ wig_so3,
                                               const float* __restrict__ bias,
                                               float* __restrict__ out) {
    __shared__ float2 Fz[NSPEC3];    // 43648 B
    __shared__ float2 S[31 * 31];    // 7688 B
    __shared__ float2 G[31 * 32];    // 7936 B
    __shared__ float2 tw[32];        // e^{+2pi i q/32}
    const int bo = blockIdx.x;
    const int b = bo >> 6, o = bo & 63;
    const int tid = threadIdx.x;

    if (tid < 32) {
        float s_, c_;
        sincosf(2.0f * PI_F * (float)tid / 32.0f, &s_, &c_);
        tw[tid] = make_float2(c_, s_);
    }

    // Phase A: Fz[l,mm,nn] = sum_i fhat[l^2+mm, b, i] * psic[l^2+nn, o, i]
    for (int t = tid; t < NSPEC3; t += 256) {
        int l = 15;
        while (c_off[l] > t) --l;
        const int L = 2 * l + 1;
        const int r = t - c_off[l];
        const int mm = r / L;
        const int nn = r - mm * L;
        const float2* fh = fhat + ((size_t)(l * l + mm) * BATCH + b) * F_IN;
        const float2* ps = psic + ((size_t)(l * l + nn) * F_OUT + o) * F_IN;
        float re = 0.f, im = 0.f;
        for (int i = 0; i < F_IN; ++i) {
            const float2 a = fh[i], c = ps[i];
            re += a.x * c.x - a.y * c.y;
            im += a.x * c.y + a.y * c.x;
        }
        Fz[t] = make_float2(re, im);
    }
    __syncthreads();

    const float bb = bias[o];
    float* obase = out + (size_t)bo * 32768;

    for (int k = 0; k < 32; ++k) {
        const float* wrow = wig_so3 + (size_t)k * NSPEC3;
        // S[m,n] = sum_l Fz[l,m,n] * wig_so3[k, l, m, n]
        for (int t = tid; t < 31 * 31; t += 256) {
            const int mr = t / 31, nr = t - mr * 31;
            const int m = mr - 15, n = nr - 15;
            const int am = m < 0 ? -m : m;
            const int an = n < 0 ? -n : n;
            const int lmin = am > an ? am : an;
            float re = 0.f, im = 0.f;
            for (int l = lmin; l < 16; ++l) {
                const int idx = c_off[l] + (m + l) * (2 * l + 1) + (n + l);
                const float w = wrow[idx];
                const float2 fz = Fz[idx];
                re += fz.x * w;
                im += fz.y * w;
            }
            S[t] = make_float2(re, im);
        }
        __syncthreads();
        // G[m,g] = sum_n S[m,n] e^{+2pi i n g/32}
        for (int t = tid; t < 31 * 32; t += 256) {
            const int mr = t >> 5, g = t & 31;
            float re = 0.f, im = 0.f;
            const float2* srow = &S[mr * 31];
            for (int nr = 0; nr < 31; ++nr) {
                const float2 sv = srow[nr];
                const float2 w = tw[((nr - 15) * g) & 31];
                re += sv.x * w.x - sv.y * w.y;
                im += sv.x * w.y + sv.y * w.x;
            }
            G[t] = make_float2(re, im);
        }
        __syncthreads();
        // out[a,g] = Re sum_m G[m,g] e^{+2pi i m a/32} + bias
        for (int t = tid; t < 1024; t += 256) {
            const int a = t >> 5, g = t & 31;
            float acc = bb;
            for (int mr = 0; mr < 31; ++mr) {
                const float2 gv = G[mr * 32 + g];
                const float2 w = tw[((mr - 15) * a) & 31];
                acc += gv.x * w.x - gv.y * w.y;
            }
            obase[k * 1024 + t] = acc;
        }
        __syncthreads();
    }
}

extern "C" void kernel_launch(void* const* d_in, const int* in_sizes, int n_in,
                              void* d_out, int out_size, void* d_ws, size_t ws_size,
                              hipStream_t stream) {
    const float* x       = (const float*)d_in[0];
    const float* kern    = (const float*)d_in[1];
    const float* bias    = (const float*)d_in[2];
    const float* wig_s2  = (const float*)d_in[3];
    const float* fk_re   = (const float*)d_in[4];
    const float* fk_im   = (const float*)d_in[5];
    const float* wig_so3 = (const float*)d_in[6];
    float* out = (float*)d_out;

    // workspace layout
    float2* fhat = (float2*)d_ws;                            // 256*16*16 float2 = 512 KB
    float2* psic = (float2*)((char*)d_ws + (512u << 10));    // 256*64*16 float2 = 2 MB

    k1_fhat<<<BATCH * F_IN, 256, 0, stream>>>(x, wig_s2, fhat);
    k2_psic<<<NSPEC, 256, 0, stream>>>(kern, fk_re, fk_im, psic);
    k3_main<<<BATCH * F_OUT, 256, 0, stream>>>(fhat, psic, wig_so3, bias, out);
}